// Round 3
// baseline (497.728 us; speedup 1.0000x reference)
//
#include <hip/hip_runtime.h>

typedef _Float16 f16;
typedef __attribute__((ext_vector_type(2))) __fp16   f16x2;  // matches cvt_pkrtz return type
typedef __attribute__((ext_vector_type(8))) _Float16 f16x8;
typedef __attribute__((ext_vector_type(4))) float    f32x4;

#define NP 13          // Wn0..6 -> p=0..6, Ws0..5 -> p=7..12; result = outputs[7]
#define THREADS 1024   // 16 waves/block, 1 block/CU (LDS ~107 KB) -> 4 waves/SIMD (R6: was 512/2 waves)
#define NBLOCKS 256
#define TILES 2        // 4096 waves * 2 tiles * 32 rows = 262144

// Verified (R2-R5) conventions for mfma_f32_16x16x32_f16, D[m][n]=sum_k A[m][k]B[n][k]:
//   A/B frag: lane(q=lane>>4, l15=lane&15) holds [m|n = l15][k = q*8+j], j=0..7
//   C/D:      col(n)=l15, row(m)=q*4+reg
// A = W (m = output feature), B = h (n = batch row). C feeds next layer's B-frag with
// no cross-lane movement via the k-slot permutation baked into the LDS weight layout:
//   chunk ch = kb*4+q holds features kb*32 + jh*16 + q*4 + jl, XOR-swizzled by f&7.
// R6 addressing insight: f&7 = l15&7 (ft*16 = 0 mod 8), so the swizzled chunk index is
// ft-independent -> 2 per-lane base pointers (kb=0/1), all weight reads become
// base + compile-time immediate (p*8192 + ft*2048 bytes; skip base pre-biased +7 mats).
//
// Empirical law (R3/R4/R5): toolchain pins VGPR_Count at 128; stay under it.
// 3-buffer rotation (period 3) replaces hp/hp2/hnew copies: 48 VGPR for h-state, 0 movs.
//
// R8 = R6 with the f16x2 element type fixed to __fp16 (cvt_pkrtz's return type).

union frag { f16x8 v; f16x2 h[4]; };   // same 128-bit layout, element types both IEEE half

__global__ __launch_bounds__(THREADS)
void nn_fused(const float* __restrict__ x,
              const float* __restrict__ Wn, const float* __restrict__ bn,
              const float* __restrict__ Ws, const float* __restrict__ bs,
              float* __restrict__ out)
{
    __shared__ __attribute__((aligned(16))) f16   w_lds[NP * 4096]; // [p][f=64][slot=64]
    __shared__ __attribute__((aligned(16))) float b_lds[NP * 64];   // plain f-major (R6: was r-strided)

    const int tid = threadIdx.x;

    // ---- stage weights (unchanged layout; RTN casts preserve weight accuracy) ----
    for (int c = tid; c < NP * 512; c += THREADS) {
        const int p = c >> 9, f = (c >> 3) & 63, ch = c & 7;
        const int kb = ch >> 2, qq = ch & 3;
        const float* src = (p < 7 ? Wn + p * 4096 : Ws + (p - 7) * 4096) + f * 64;
        f32x4 a, b;
        __builtin_memcpy(&a, src + kb * 32 + qq * 4, 16);       // jh=0
        __builtin_memcpy(&b, src + kb * 32 + 16 + qq * 4, 16);  // jh=1
        f16x8 v;
        v[0]=(f16)a.x; v[1]=(f16)a.y; v[2]=(f16)a.z; v[3]=(f16)a.w;
        v[4]=(f16)b.x; v[5]=(f16)b.y; v[6]=(f16)b.z; v[7]=(f16)b.w;
        __builtin_memcpy(&w_lds[p * 4096 + f * 64 + ((ch ^ (f & 7)) << 3)], &v, 16);
    }
    // biases f-major: one ds_read_b128 broadcast per (p,ft); lanes of same q share an
    // address, q=0..3 hit byte offsets 0/16/32/48 -> banks 0-15, conflict-free.
    for (int i = tid; i < NP * 64; i += THREADS) {
        const int p = i >> 6, f = i & 63;
        b_lds[i] = (p < 7) ? bn[p * 64 + f] : bs[(p - 7) * 64 + f];
    }
    __syncthreads();   // only barrier in the kernel

    const int lane = tid & 63;
    const int wid  = tid >> 6;
    const int l15  = lane & 15;
    const int q    = lane >> 4;
    const int q4   = q * 4;
    const int gw   = blockIdx.x * (THREADS / 64) + wid;   // 0..4095

    const int f7 = l15 & 7;
    const f16* wbn0 = &w_lds[l15 * 64 + ((q    ) ^ f7) * 8];  // kb=0 chunk base
    const f16* wbn1 = &w_lds[l15 * 64 + ((4 + q) ^ f7) * 8];  // kb=1 chunk base
    const f16* wbs0 = wbn0 + 7 * 4096;                        // skip-matrix bases (p>=7)
    const f16* wbs1 = wbn1 + 7 * 4096;
    const f16x2 z2 = { (__fp16)0.0f, (__fp16)0.0f };

// full layer: OUT = relu(IN1 Wn[PN]^T + bn[PN]) + relu(IN2 Ws[PS7]^T + bs[7+PS7]) in f16
#define LAYER(PN, PS7, IN1, IN2, OUT)                                                         \
    {                                                                                         \
        _Pragma("unroll")                                                                     \
        for (int ft = 0; ft < 4; ++ft) {                                                      \
            f16x8 wn0, wn1, ws0, ws1;                                                         \
            __builtin_memcpy(&wn0, wbn0 + (PN) * 4096 + ft * 1024, 16);                       \
            __builtin_memcpy(&wn1, wbn1 + (PN) * 4096 + ft * 1024, 16);                       \
            __builtin_memcpy(&ws0, wbs0 + (PS7) * 4096 + ft * 1024, 16);                      \
            __builtin_memcpy(&ws1, wbs1 + (PS7) * 4096 + ft * 1024, 16);                      \
            f32x4 bnv, bsv;                                                                   \
            __builtin_memcpy(&bnv, &b_lds[(PN) * 64 + ft * 16 + q4], 16);                     \
            __builtin_memcpy(&bsv, &b_lds[(7 + (PS7)) * 64 + ft * 16 + q4], 16);              \
            _Pragma("unroll")                                                                 \
            for (int nb = 0; nb < 2; ++nb) {                                                  \
                f32x4 an = bnv, as = bsv;                                                     \
                an = __builtin_amdgcn_mfma_f32_16x16x32_f16(wn0, IN1[nb][0].v, an, 0, 0, 0);  \
                an = __builtin_amdgcn_mfma_f32_16x16x32_f16(wn1, IN1[nb][1].v, an, 0, 0, 0);  \
                as = __builtin_amdgcn_mfma_f32_16x16x32_f16(ws0, IN2[nb][0].v, as, 0, 0, 0);  \
                as = __builtin_amdgcn_mfma_f32_16x16x32_f16(ws1, IN2[nb][1].v, as, 0, 0, 0);  \
                f16x2 r0 = __builtin_elementwise_max(__builtin_amdgcn_cvt_pkrtz(an[0], an[1]), z2)  \
                         + __builtin_elementwise_max(__builtin_amdgcn_cvt_pkrtz(as[0], as[1]), z2); \
                f16x2 r1 = __builtin_elementwise_max(__builtin_amdgcn_cvt_pkrtz(an[2], an[3]), z2)  \
                         + __builtin_elementwise_max(__builtin_amdgcn_cvt_pkrtz(as[2], as[3]), z2); \
                OUT[nb][ft >> 1].h[(ft & 1) * 2]     = r0;                                    \
                OUT[nb][ft >> 1].h[(ft & 1) * 2 + 1] = r1;                                    \
            }                                                                                 \
        }                                                                                     \
    }

#pragma unroll 1
    for (int t = 0; t < TILES; ++t) {
        const long row0 = ((long)gw + (long)t * (NBLOCKS * THREADS / 64)) * 32;

        frag BA[2][2], BB[2][2], BC[2][2];   // 3 rotating h buffers, 48 VGPR total

        // ---- x -> B-frags in BB (h0) ----
#pragma unroll
        for (int nb = 0; nb < 2; ++nb) {
            const float* xr = x + (row0 + nb * 16 + l15) * 64;
#pragma unroll
            for (int kb = 0; kb < 2; ++kb) {
                f32x4 a, b;
                __builtin_memcpy(&a, xr + kb * 32 + q4, 16);
                __builtin_memcpy(&b, xr + kb * 32 + 16 + q4, 16);
                BB[nb][kb].h[0] = __builtin_amdgcn_cvt_pkrtz(a.x, a.y);
                BB[nb][kb].h[1] = __builtin_amdgcn_cvt_pkrtz(a.z, a.w);
                BB[nb][kb].h[2] = __builtin_amdgcn_cvt_pkrtz(b.x, b.y);
                BB[nb][kb].h[3] = __builtin_amdgcn_cvt_pkrtz(b.z, b.w);
            }
        }

        // ---- layer 1: BA = h1 = relu(x Wn0^T + bn0) ----
#pragma unroll
        for (int ft = 0; ft < 4; ++ft) {
            f16x8 w0, w1;
            __builtin_memcpy(&w0, wbn0 + ft * 1024, 16);   // p=0
            __builtin_memcpy(&w1, wbn1 + ft * 1024, 16);
            f32x4 bv;
            __builtin_memcpy(&bv, &b_lds[ft * 16 + q4], 16);
#pragma unroll
            for (int nb = 0; nb < 2; ++nb) {
                f32x4 an = bv;
                an = __builtin_amdgcn_mfma_f32_16x16x32_f16(w0, BB[nb][0].v, an, 0, 0, 0);
                an = __builtin_amdgcn_mfma_f32_16x16x32_f16(w1, BB[nb][1].v, an, 0, 0, 0);
                BA[nb][ft >> 1].h[(ft & 1) * 2] =
                    __builtin_elementwise_max(__builtin_amdgcn_cvt_pkrtz(an[0], an[1]), z2);
                BA[nb][ft >> 1].h[(ft & 1) * 2 + 1] =
                    __builtin_elementwise_max(__builtin_amdgcn_cvt_pkrtz(an[2], an[3]), z2);
            }
        }

        // ---- layers 2..6, period-3 buffer rotation (in1=h_{l-1}, in2=h_{l-2}, out over dead) ----
        LAYER(1, 0, BA, BB, BC);   // l=2: h2
        LAYER(2, 1, BC, BA, BB);   // l=3: h3
        LAYER(3, 2, BB, BC, BA);   // l=4: h4
        LAYER(4, 3, BA, BB, BC);   // l=5: h5
        LAYER(5, 4, BC, BA, BB);   // l=6: h6

        // ---- layer 7: out = relu(h6 Wn6^T + bn6) + relu(h5 Ws5^T + bs5), fp32 store ----
#pragma unroll
        for (int ft = 0; ft < 4; ++ft) {
            f16x8 wn0, wn1, ws0, ws1;
            __builtin_memcpy(&wn0, wbn0 + 6 * 4096 + ft * 1024, 16);
            __builtin_memcpy(&wn1, wbn1 + 6 * 4096 + ft * 1024, 16);
            __builtin_memcpy(&ws0, wbs0 + 5 * 4096 + ft * 1024, 16);
            __builtin_memcpy(&ws1, wbs1 + 5 * 4096 + ft * 1024, 16);
            f32x4 bnv, bsv;
            __builtin_memcpy(&bnv, &b_lds[6 * 64 + ft * 16 + q4], 16);
            __builtin_memcpy(&bsv, &b_lds[12 * 64 + ft * 16 + q4], 16);
#pragma unroll
            for (int nb = 0; nb < 2; ++nb) {
                f32x4 an = bnv, as = bsv;
                an = __builtin_amdgcn_mfma_f32_16x16x32_f16(wn0, BB[nb][0].v, an, 0, 0, 0);
                an = __builtin_amdgcn_mfma_f32_16x16x32_f16(wn1, BB[nb][1].v, an, 0, 0, 0);
                as = __builtin_amdgcn_mfma_f32_16x16x32_f16(ws0, BC[nb][0].v, as, 0, 0, 0);
                as = __builtin_amdgcn_mfma_f32_16x16x32_f16(ws1, BC[nb][1].v, as, 0, 0, 0);
                f32x4 v;
#pragma unroll
                for (int r = 0; r < 4; ++r) v[r] = fmaxf(an[r], 0.f) + fmaxf(as[r], 0.f);
                float* orow = out + (row0 + nb * 16 + l15) * 64;
                __builtin_memcpy(orow + ft * 16 + q4, &v, 16);
            }
        }
    }
#undef LAYER
}

extern "C" void kernel_launch(void* const* d_in, const int* in_sizes, int n_in,
                              void* d_out, int out_size, void* d_ws, size_t ws_size,
                              hipStream_t stream) {
    (void)in_sizes; (void)n_in; (void)d_ws; (void)ws_size; (void)out_size;
    const float* x  = (const float*)d_in[0];
    const float* Wn = (const float*)d_in[1];
    const float* bn = (const float*)d_in[2];
    const float* Ws = (const float*)d_in[3];
    const float* bs = (const float*)d_in[4];
    nn_fused<<<dim3(NBLOCKS), dim3(THREADS), 0, stream>>>(x, Wn, bn, Ws, bs, (float*)d_out);
}